// Round 1
// baseline (599.074 us; speedup 1.0000x reference)
//
#include <hip/hip_runtime.h>

#define M_DIM 8192
#define K_DIM 2048
#define N_DIM 5632

typedef __attribute__((ext_vector_type(8))) short short8;
typedef __attribute__((ext_vector_type(4))) float f32x4;

// fp32 -> bf16 round-to-nearest-even (bit trick; inputs are finite)
__device__ __forceinline__ short f2b(float f) {
  union { float f; unsigned u; } v; v.f = f;
  unsigned r = v.u + 0x7FFFu + ((v.u >> 16) & 1u);
  return (short)(r >> 16);
}

// async global->LDS, 16B per lane. LDS dest must be wave-uniform base + lane*16.
__device__ __forceinline__ void async16(void* lds, const void* g) {
  __builtin_amdgcn_global_load_lds(
      (const __attribute__((address_space(1))) unsigned*)g,
      (__attribute__((address_space(3))) unsigned*)lds,
      16, 0, 0);
}

// ---------------- Kernel 1: x fp32 -> bf16 -----------------------------------
__global__ __launch_bounds__(256) void cvt_x_kernel(const float* __restrict__ x,
                                                    short* __restrict__ xb) {
  long t = (long)blockIdx.x * 256 + threadIdx.x;   // 8 elements per thread
  const float4* xv = (const float4*)x;
  float4 f0 = xv[2 * t];
  float4 f1 = xv[2 * t + 1];
  short8 o;
  o[0] = f2b(f0.x); o[1] = f2b(f0.y); o[2] = f2b(f0.z); o[3] = f2b(f0.w);
  o[4] = f2b(f1.x); o[5] = f2b(f1.y); o[6] = f2b(f1.z); o[7] = f2b(f1.w);
  *(short8*)(xb + 8 * t) = o;
}

// ---------------- Kernel 2: dequant int4 + fold rank-16 LoRA into W' ---------
// W'[o][i] = (q - zero[g]) * scale[g] + 2 * sum_r A[i][r] * B[r][o]
// One block per output row o (256 threads x 8 elements = 2048 = IN).
__global__ __launch_bounds__(256) void dequant_lora_kernel(
    const int* __restrict__ packed, const float* __restrict__ scales,
    const float* __restrict__ zeros, const float* __restrict__ lA,
    const float* __restrict__ lB, short* __restrict__ wb) {
  int o = blockIdx.x;
  int i0 = threadIdx.x * 8;                  // first of 8 W elements in row o
  long e0 = (long)o * K_DIM + i0;            // flat W index
  int4 p = ((const int4*)packed)[e0 >> 3];   // 4 packed bytes -> 8 codes
  int g = (int)(e0 >> 7);                    // group of 128 (8 | 128, same group)
  float s = scales[g], z = zeros[g];

  // B column for this o, pre-scaled by lora 2.0 (uniform per block -> L1 broadcast)
  float bcol[16];
#pragma unroll
  for (int r = 0; r < 16; ++r) bcol[r] = lB[r * N_DIM + o] * 2.0f;

  short8 out8;
#pragma unroll
  for (int d = 0; d < 4; ++d) {
    int pv = (&p.x)[d];                      // value 0..255, two nibbles
    float w0 = ((float)(pv & 0xF) - z) * s;        // element e0+2d   (low)
    float w1 = ((float)((pv >> 4) & 0xF) - z) * s; // element e0+2d+1 (high)
    const float4* a0 = (const float4*)&lA[(i0 + 2 * d) * 16];
    const float4* a1 = (const float4*)&lA[(i0 + 2 * d + 1) * 16];
    float acc0 = 0.f, acc1 = 0.f;
#pragma unroll
    for (int r4 = 0; r4 < 4; ++r4) {
      float4 av0 = a0[r4], av1 = a1[r4];
      acc0 += av0.x * bcol[4 * r4] + av0.y * bcol[4 * r4 + 1] +
              av0.z * bcol[4 * r4 + 2] + av0.w * bcol[4 * r4 + 3];
      acc1 += av1.x * bcol[4 * r4] + av1.y * bcol[4 * r4 + 1] +
              av1.z * bcol[4 * r4 + 2] + av1.w * bcol[4 * r4 + 3];
    }
    out8[2 * d] = f2b(w0 + acc0);
    out8[2 * d + 1] = f2b(w1 + acc1);
  }
  *(short8*)(wb + e0) = out8;
}

// ---------------- Kernel 3: C[m][n] = sum_k X[m][k] * W'[n][k] ---------------
// m97 structure: 128x128 tile, BK=64, 4 waves (2x2), 4x4 16x16x32 frags/wave,
// global_load_lds width-16 staging, 2-barrier K-loop, ds_read_b128 frag loads.
__global__ __launch_bounds__(256) void gemm_kernel(const short* __restrict__ xb,
                                                   const short* __restrict__ wb,
                                                   float* __restrict__ out) {
  __shared__ __align__(16) short As[128 * 64];  // 16 KB, lane-ordered (no pad)
  __shared__ __align__(16) short Bs[128 * 64];  // 16 KB

  const int tid = threadIdx.x;
  const int wave = tid >> 6, lane = tid & 63;
  const int wm = wave >> 1, wn = wave & 1;      // 2x2 wave grid, 64x64 each
  const int l15 = lane & 15, quad = lane >> 4;
  const int m0 = blockIdx.y * 128, n0 = blockIdx.x * 128;
  const short* a_base = xb + (size_t)m0 * K_DIM;
  const short* b_base = wb + (size_t)n0 * K_DIM;

  f32x4 acc[4][4] = {};

  for (int k0 = 0; k0 < K_DIM; k0 += 64) {
    __syncthreads();  // previous tile's LDS reads done before overwrite
#pragma unroll
    for (int it = 0; it < 4; ++it) {
      int gi = it * 256 + tid;      // 16B-chunk id 0..1023; lane-contiguous
      int row = gi >> 3;            // tile row 0..127
      int c8 = gi & 7;              // which 8-bf16 chunk along K
      async16(&As[gi * 8], a_base + (size_t)row * K_DIM + k0 + c8 * 8);
      async16(&Bs[gi * 8], b_base + (size_t)row * K_DIM + k0 + c8 * 8);
    }
    __syncthreads();  // compiler emits vmcnt(0) drain -> LDS ready

#pragma unroll
    for (int ks = 0; ks < 2; ++ks) {
      short8 af[4], bf[4];
#pragma unroll
      for (int mi = 0; mi < 4; ++mi)
        af[mi] = *(const short8*)&As[(wm * 64 + mi * 16 + l15) * 64 + ks * 32 + quad * 8];
#pragma unroll
      for (int ni = 0; ni < 4; ++ni)
        bf[ni] = *(const short8*)&Bs[(wn * 64 + ni * 16 + l15) * 64 + ks * 32 + quad * 8];
#pragma unroll
      for (int mi = 0; mi < 4; ++mi)
#pragma unroll
        for (int ni = 0; ni < 4; ++ni)
          acc[mi][ni] = __builtin_amdgcn_mfma_f32_16x16x32_bf16(
              af[mi], bf[ni], acc[mi][ni], 0, 0, 0);
    }
  }

  // Epilogue: C/D layout col = lane&15, row = quad*4 + reg  [m89-verified]
  float* op = out + (size_t)(m0 + wm * 64 + quad * 4) * N_DIM + n0 + wn * 64 + l15;
#pragma unroll
  for (int mi = 0; mi < 4; ++mi)
#pragma unroll
    for (int r = 0; r < 4; ++r)
#pragma unroll
      for (int ni = 0; ni < 4; ++ni)
        op[(size_t)(mi * 16 + r) * N_DIM + ni * 16] = acc[mi][ni][r];
}

// -----------------------------------------------------------------------------
extern "C" void kernel_launch(void* const* d_in, const int* in_sizes, int n_in,
                              void* d_out, int out_size, void* d_ws, size_t ws_size,
                              hipStream_t stream) {
  const float* x      = (const float*)d_in[0];  // [4,2048,2048] fp32
  const int*   packed = (const int*)d_in[1];    // [5767168] int32 (byte values)
  const float* scales = (const float*)d_in[2];  // [90112]
  const float* zeros  = (const float*)d_in[3];  // [90112]
  const float* lA     = (const float*)d_in[4];  // [2048,16]
  const float* lB     = (const float*)d_in[5];  // [16,5632]
  float* out = (float*)d_out;                   // [4,2048,5632] fp32

  short* xb = (short*)d_ws;                     // x in bf16: 16,777,216 shorts
  short* wb = xb + (size_t)M_DIM * K_DIM;       // W' in bf16: 11,534,336 shorts

  cvt_x_kernel<<<(M_DIM * K_DIM) / (256 * 8), 256, 0, stream>>>(x, xb);
  dequant_lora_kernel<<<N_DIM, 256, 0, stream>>>(packed, scales, zeros, lA, lB, wb);
  gemm_kernel<<<dim3(N_DIM / 128, M_DIM / 128), 256, 0, stream>>>(xb, wb, out);
}

// Round 2
// 561.579 us; speedup vs baseline: 1.0668x; 1.0668x over previous
//
#include <hip/hip_runtime.h>

#define M_DIM 8192
#define K_DIM 2048
#define N_DIM 5632

typedef __attribute__((ext_vector_type(8))) short short8;
typedef __attribute__((ext_vector_type(4))) float f32x4;

// fp32 -> bf16 round-to-nearest-even (bit trick; inputs are finite)
__device__ __forceinline__ short f2b(float f) {
  union { float f; unsigned u; } v; v.f = f;
  unsigned r = v.u + 0x7FFFu + ((v.u >> 16) & 1u);
  return (short)(r >> 16);
}

// async global->LDS, 16B per lane. LDS dest must be wave-uniform base + lane*16.
__device__ __forceinline__ void async16(void* lds, const void* g) {
  __builtin_amdgcn_global_load_lds(
      (const __attribute__((address_space(1))) unsigned*)g,
      (__attribute__((address_space(3))) unsigned*)lds,
      16, 0, 0);
}

// ---------------- Kernel 1: x fp32 -> bf16 -----------------------------------
__global__ __launch_bounds__(256) void cvt_x_kernel(const float* __restrict__ x,
                                                    short* __restrict__ xb) {
  long t = (long)blockIdx.x * 256 + threadIdx.x;   // 8 elements per thread
  const float4* xv = (const float4*)x;
  float4 f0 = xv[2 * t];
  float4 f1 = xv[2 * t + 1];
  short8 o;
  o[0] = f2b(f0.x); o[1] = f2b(f0.y); o[2] = f2b(f0.z); o[3] = f2b(f0.w);
  o[4] = f2b(f1.x); o[5] = f2b(f1.y); o[6] = f2b(f1.z); o[7] = f2b(f1.w);
  *(short8*)(xb + 8 * t) = o;
}

// ---------------- Kernel 2: dequant int4 + fold rank-16 LoRA into W' ---------
// W'[o][i] = (q - zero[g]) * scale[g] + 2 * sum_r A[i][r] * B[r][o]
__global__ __launch_bounds__(256) void dequant_lora_kernel(
    const int* __restrict__ packed, const float* __restrict__ scales,
    const float* __restrict__ zeros, const float* __restrict__ lA,
    const float* __restrict__ lB, short* __restrict__ wb) {
  int o = blockIdx.x;
  int i0 = threadIdx.x * 8;                  // first of 8 W elements in row o
  long e0 = (long)o * K_DIM + i0;            // flat W index
  int4 p = ((const int4*)packed)[e0 >> 3];   // 4 packed bytes -> 8 codes
  int g = (int)(e0 >> 7);                    // group of 128 (8 | 128, same group)
  float s = scales[g], z = zeros[g];

  // B column for this o, pre-scaled by lora 2.0 (uniform per block)
  float bcol[16];
#pragma unroll
  for (int r = 0; r < 16; ++r) bcol[r] = lB[r * N_DIM + o] * 2.0f;

  short8 out8;
#pragma unroll
  for (int d = 0; d < 4; ++d) {
    int pv = (&p.x)[d];                      // two nibbles
    float w0 = ((float)(pv & 0xF) - z) * s;        // element e0+2d   (low)
    float w1 = ((float)((pv >> 4) & 0xF) - z) * s; // element e0+2d+1 (high)
    const float4* a0 = (const float4*)&lA[(i0 + 2 * d) * 16];
    const float4* a1 = (const float4*)&lA[(i0 + 2 * d + 1) * 16];
    float acc0 = 0.f, acc1 = 0.f;
#pragma unroll
    for (int r4 = 0; r4 < 4; ++r4) {
      float4 av0 = a0[r4], av1 = a1[r4];
      acc0 += av0.x * bcol[4 * r4] + av0.y * bcol[4 * r4 + 1] +
              av0.z * bcol[4 * r4 + 2] + av0.w * bcol[4 * r4 + 3];
      acc1 += av1.x * bcol[4 * r4] + av1.y * bcol[4 * r4 + 1] +
              av1.z * bcol[4 * r4 + 2] + av1.w * bcol[4 * r4 + 3];
    }
    out8[2 * d] = f2b(w0 + acc0);
    out8[2 * d + 1] = f2b(w1 + acc1);
  }
  *(short8*)(wb + e0) = out8;
}

// ---------------- Kernel 3: C[m][n] = sum_k X[m][k] * W'[n][k] ---------------
// 128x128 tile, BK=64, 4 waves (2x2), 4x4 16x16x32 frags/wave.
// LDS layout XOR-swizzled: chunk c of row r lives at slot (c ^ (r&7)).
// Read banks: ((c^(l&7))*4)%32 -> all 32 banks, 2-way alias only (free, m136).
__global__ __launch_bounds__(256) void gemm_kernel(const short* __restrict__ xb,
                                                   const short* __restrict__ wb,
                                                   float* __restrict__ out) {
  __shared__ __align__(16) short As[128 * 64];  // 16 KB
  __shared__ __align__(16) short Bs[128 * 64];  // 16 KB

  const int tid = threadIdx.x;
  const int wave = tid >> 6, lane = tid & 63;
  const int wm = wave >> 1, wn = wave & 1;      // 2x2 wave grid, 64x64 each
  const int l15 = lane & 15, quad = lane >> 4;
  const int m0 = blockIdx.y * 128, n0 = blockIdx.x * 128;
  const short* a_base = xb + (size_t)m0 * K_DIM;
  const short* b_base = wb + (size_t)n0 * K_DIM;

  f32x4 acc[4][4] = {};

  // Precompute swizzled staging source offsets (row, chunk) per slot.
  // gi = it*256 + tid; row = gi>>3; slot = gi&7; chunk = slot ^ (row&7).
  // Precompute swizzled LDS read offsets (k0-invariant).
  int a_off[2][4], b_off[2][4];
#pragma unroll
  for (int ks = 0; ks < 2; ++ks) {
    int c = ks * 4 + quad;                       // chunk index 0..7
#pragma unroll
    for (int i = 0; i < 4; ++i) {
      int ra = wm * 64 + i * 16 + l15;
      int rb = wn * 64 + i * 16 + l15;
      a_off[ks][i] = (ra * 8 + (c ^ (ra & 7))) * 8;  // shorts
      b_off[ks][i] = (rb * 8 + (c ^ (rb & 7))) * 8;
    }
  }

  for (int k0 = 0; k0 < K_DIM; k0 += 64) {
    __syncthreads();  // previous tile's LDS reads done before overwrite
#pragma unroll
    for (int it = 0; it < 4; ++it) {
      int gi = it * 256 + tid;        // 16B-chunk id 0..1023; lane-contiguous LDS
      int row = gi >> 3;              // tile row 0..127
      int c = (gi & 7) ^ (row & 7);   // swizzle: slot gi&7 holds chunk c
      async16(&As[gi * 8], a_base + (size_t)row * K_DIM + k0 + c * 8);
      async16(&Bs[gi * 8], b_base + (size_t)row * K_DIM + k0 + c * 8);
    }
    __syncthreads();  // vmcnt(0) drain -> LDS ready

#pragma unroll
    for (int ks = 0; ks < 2; ++ks) {
      short8 af[4], bf[4];
#pragma unroll
      for (int mi = 0; mi < 4; ++mi) af[mi] = *(const short8*)&As[a_off[ks][mi]];
#pragma unroll
      for (int ni = 0; ni < 4; ++ni) bf[ni] = *(const short8*)&Bs[b_off[ks][ni]];
#pragma unroll
      for (int mi = 0; mi < 4; ++mi)
#pragma unroll
        for (int ni = 0; ni < 4; ++ni)
          acc[mi][ni] = __builtin_amdgcn_mfma_f32_16x16x32_bf16(
              af[mi], bf[ni], acc[mi][ni], 0, 0, 0);
    }
  }

  // Epilogue: C/D layout col = lane&15, row = quad*4 + reg  [m89-verified]
  float* op = out + (size_t)(m0 + wm * 64 + quad * 4) * N_DIM + n0 + wn * 64 + l15;
#pragma unroll
  for (int mi = 0; mi < 4; ++mi)
#pragma unroll
    for (int r = 0; r < 4; ++r)
#pragma unroll
      for (int ni = 0; ni < 4; ++ni)
        op[(size_t)(mi * 16 + r) * N_DIM + ni * 16] = acc[mi][ni][r];
}

// -----------------------------------------------------------------------------
extern "C" void kernel_launch(void* const* d_in, const int* in_sizes, int n_in,
                              void* d_out, int out_size, void* d_ws, size_t ws_size,
                              hipStream_t stream) {
  const float* x      = (const float*)d_in[0];  // [4,2048,2048] fp32
  const int*   packed = (const int*)d_in[1];    // [5767168] int32 (byte values)
  const float* scales = (const float*)d_in[2];  // [90112]
  const float* zeros  = (const float*)d_in[3];  // [90112]
  const float* lA     = (const float*)d_in[4];  // [2048,16]
  const float* lB     = (const float*)d_in[5];  // [16,5632]
  float* out = (float*)d_out;                   // [4,2048,5632] fp32

  short* xb = (short*)d_ws;                     // x in bf16: 16,777,216 shorts
  short* wb = xb + (size_t)M_DIM * K_DIM;       // W' in bf16: 11,534,336 shorts

  cvt_x_kernel<<<(M_DIM * K_DIM) / (256 * 8), 256, 0, stream>>>(x, xb);
  dequant_lora_kernel<<<N_DIM, 256, 0, stream>>>(packed, scales, zeros, lA, lB, wb);
  gemm_kernel<<<dim3(N_DIM / 128, M_DIM / 128), 256, 0, stream>>>(xb, wb, out);
}